// Round 1
// baseline (2280.622 us; speedup 1.0000x reference)
//
#include <hip/hip_runtime.h>
#include <hip/hip_bf16.h>

// Problem constants (match reference).
#define VOCAB  50257
#define D_EMB  128
#define HID    256
#define N_CLS  2
#define BSZ    256
#define T_LEN  2048

// ---------------------------------------------------------------------------
// Kernel 1: table_ax[v][j] = sum_d emb_table[v][d] * wx_w[d][j] + wx_b[j]
// 3.3 GFLOP, fully parallel. 32 vocab rows per block, emb rows staged in LDS
// (broadcast reads, conflict-free), wx_w streamed from L2 (128 KB, resident).
// ---------------------------------------------------------------------------
__global__ __launch_bounds__(256)
void tabax_kernel(const float* __restrict__ emb,
                  const float* __restrict__ wxw,
                  const float* __restrict__ wxb,
                  float* __restrict__ tab)
{
    const int j  = threadIdx.x;          // output unit 0..255
    const int v0 = blockIdx.x * 32;
    const int rows = min(32, VOCAB - v0);

    __shared__ float ebuf[32 * D_EMB];   // 16 KB
    for (int i = j; i < rows * D_EMB; i += 256)
        ebuf[i] = emb[(size_t)v0 * D_EMB + i];
    __syncthreads();

    float acc[32];
#pragma unroll
    for (int r = 0; r < 32; ++r) acc[r] = 0.f;

#pragma unroll 8
    for (int d = 0; d < D_EMB; ++d) {
        float wxv = wxw[d * HID + j];    // coalesced
#pragma unroll
        for (int r = 0; r < 32; ++r)
            acc[r] = fmaf(ebuf[r * D_EMB + d], wxv, acc[r]); // LDS broadcast
    }

    const float bb = wxb[j];
    for (int r = 0; r < rows; ++r)
        tab[(size_t)(v0 + r) * HID + j] = acc[r] + bb;       // coalesced
}

// ---------------------------------------------------------------------------
// Kernel 2: sequential recurrence. One block per batch row (256 blocks = 256
// CUs). 512 threads: thread (j = tid>>1, half = tid&1) owns half of wh_w
// column j in registers (128 f32). h double-buffered in LDS; one barrier per
// step. ax row for step t+1 prefetched during step t.
// USE_TAB: read precomputed table_ax from d_ws. Fallback (!USE_TAB): stage
// emb row in LDS each step and apply wx half-column from registers.
// ---------------------------------------------------------------------------
__device__ __forceinline__ float fast_tanh(float x) {
    // tanh(x) = 1 - 2/(e^{2x}+1); v_exp_f32-based, ~1ulp exp -> <1e-6 abs err.
    float e2 = __expf(2.f * x);
    return 1.f - 2.f / (e2 + 1.f);
}

template <bool USE_TAB>
__global__ __launch_bounds__(512, 2)
void rnn_kernel(const int*   __restrict__ batch,
                const float* __restrict__ emb,
                const float* __restrict__ wxw,
                const float* __restrict__ wxb,
                const float* __restrict__ whw,
                const float* __restrict__ whb,
                const float* __restrict__ clfw,
                const float* __restrict__ clfb,
                const float* __restrict__ ax_tab,
                float*       __restrict__ out)
{
    const int b    = blockIdx.x;
    const int tid  = threadIdx.x;
    const int j    = tid >> 1;       // output unit 0..255
    const int half = tid & 1;        // k-range half
    const int k0   = half * 128;

    __shared__ float hbuf[2][HID];   // double-buffered hidden state
    __shared__ float ebuf[2][D_EMB]; // only used when !USE_TAB

    // --- one-time weight load into registers ---
    float w[128];
#pragma unroll
    for (int k = 0; k < 128; ++k)
        w[k] = whw[(size_t)(k0 + k) * HID + j];

    float wx[64];
    if constexpr (!USE_TAB) {
#pragma unroll
        for (int d = 0; d < 64; ++d)
            wx[d] = wxw[(size_t)(half * 64 + d) * HID + j];
    }

    const float bj  = whb[j];
    float axb = 0.f;
    if constexpr (!USE_TAB) axb = wxb[j];

    if (tid < HID) hbuf[0][tid] = 0.f;

    const int* brow = batch + (size_t)b * T_LEN;

    int tok_n = brow[0];             // token for step 0 initially
    float axv = 0.f;
    if constexpr (USE_TAB) {
        axv = ax_tab[(size_t)tok_n * HID + j];          // ax for t=0
    } else {
        if (tid < D_EMB) ebuf[0][tid] = emb[(size_t)tok_n * D_EMB + tid];
    }
    tok_n = brow[1];                 // token for step 1
    __syncthreads();

    float h_j = 0.f;
    int cur = 0;
    for (int t = 0; t < T_LEN; ++t) {
        const int nxt = cur ^ 1;
        // --- prefetch for t+1 (hide L2/L3 latency under the matvec) ---
        const int tok_nn = (t + 2 < T_LEN) ? brow[t + 2] : 0;
        float ax_n = 0.f;
        float ev   = 0.f;
        if constexpr (USE_TAB) {
            if (t + 1 < T_LEN) ax_n = ax_tab[(size_t)tok_n * HID + j];
        } else {
            if (t + 1 < T_LEN && tid < D_EMB)
                ev = emb[(size_t)tok_n * D_EMB + tid];
        }

        // --- recurrent half-matvec: 128 FMAs from registers, h from LDS ---
        float a0 = 0.f, a1 = 0.f, a2 = 0.f, a3 = 0.f;
        const float4* hv = (const float4*)&hbuf[cur][k0];
#pragma unroll
        for (int i = 0; i < 32; ++i) {
            float4 h4 = hv[i];                        // LDS broadcast read
            a0 = fmaf(h4.x, w[4 * i + 0], a0);
            a1 = fmaf(h4.y, w[4 * i + 1], a1);
            a2 = fmaf(h4.z, w[4 * i + 2], a2);
            a3 = fmaf(h4.w, w[4 * i + 3], a3);
        }
        if constexpr (!USE_TAB) {
            const float4* evv = (const float4*)&ebuf[cur][half * 64];
#pragma unroll
            for (int i = 0; i < 16; ++i) {
                float4 e4 = evv[i];
                a0 = fmaf(e4.x, wx[4 * i + 0], a0);
                a1 = fmaf(e4.y, wx[4 * i + 1], a1);
                a2 = fmaf(e4.z, wx[4 * i + 2], a2);
                a3 = fmaf(e4.w, wx[4 * i + 3], a3);
            }
        }
        float s = (a0 + a1) + (a2 + a3);
        s += __shfl_xor(s, 1);                        // combine the two halves

        float x;
        if constexpr (USE_TAB) x = s + bj + axv;      // bias folded in table
        else                   x = s + bj + axb;
        h_j = fast_tanh(x);

        if (half == 0) hbuf[nxt][j] = h_j;
        if constexpr (!USE_TAB) {
            if (t + 1 < T_LEN && tid < D_EMB) ebuf[nxt][tid] = ev;
        }
        __syncthreads();   // writes to [nxt] visible; [cur] reads all done

        axv   = ax_n;
        tok_n = tok_nn;
        cur   = nxt;
    }

    // --- epilogue: out[b][c] = sum_j h[j] * clf_w[j][c] + clf_b[c] ---
    if (half == 0) {
        hbuf[0][j] = h_j * clfw[j * N_CLS + 0];
        hbuf[1][j] = h_j * clfw[j * N_CLS + 1];
    }
    __syncthreads();
    if (tid < 64) {
        float v = hbuf[0][tid] + hbuf[0][tid + 64] +
                  hbuf[0][tid + 128] + hbuf[0][tid + 192];
#pragma unroll
        for (int off = 32; off > 0; off >>= 1) v += __shfl_xor(v, off);
        if (tid == 0) out[b * N_CLS + 0] = v + clfb[0];
    } else if (tid < 128) {
        const int l = tid - 64;
        float v = hbuf[1][l] + hbuf[1][l + 64] +
                  hbuf[1][l + 128] + hbuf[1][l + 192];
#pragma unroll
        for (int off = 32; off > 0; off >>= 1) v += __shfl_xor(v, off);
        if (l == 0) out[b * N_CLS + 1] = v + clfb[1];
    }
}

// ---------------------------------------------------------------------------
extern "C" void kernel_launch(void* const* d_in, const int* in_sizes, int n_in,
                              void* d_out, int out_size, void* d_ws, size_t ws_size,
                              hipStream_t stream)
{
    const int*   batch = (const int*)  d_in[0];
    const float* emb   = (const float*)d_in[1];
    const float* wxw   = (const float*)d_in[2];
    const float* wxb   = (const float*)d_in[3];
    const float* whw   = (const float*)d_in[4];
    const float* whb   = (const float*)d_in[5];
    const float* clfw  = (const float*)d_in[6];
    const float* clfb  = (const float*)d_in[7];
    float* out = (float*)d_out;

    const size_t tab_bytes = (size_t)VOCAB * HID * sizeof(float);
    if (ws_size >= tab_bytes) {
        float* tab = (float*)d_ws;
        tabax_kernel<<<(VOCAB + 31) / 32, 256, 0, stream>>>(emb, wxw, wxb, tab);
        rnn_kernel<true><<<BSZ, 512, 0, stream>>>(batch, emb, wxw, wxb, whw, whb,
                                                  clfw, clfb, tab, out);
    } else {
        rnn_kernel<false><<<BSZ, 512, 0, stream>>>(batch, emb, wxw, wxb, whw, whb,
                                                   clfw, clfb, nullptr, out);
    }
}

// Round 2
// 2061.078 us; speedup vs baseline: 1.1065x; 1.1065x over previous
//
#include <hip/hip_runtime.h>
#include <hip/hip_bf16.h>

// Problem constants (match reference).
#define VOCAB  50257
#define D_EMB  128
#define HID    256
#define N_CLS  2
#define BSZ    256
#define T_LEN  2048

// ---------------------------------------------------------------------------
// Kernel 1: tab[v][j] = sum_d emb_table[v][d] * wx_w[d][j] + wx_b[j] + wh_b[j]
// (wh_b folded in so the recurrent step needs no extra bias add).
// ---------------------------------------------------------------------------
__global__ __launch_bounds__(256)
void tabax_kernel(const float* __restrict__ emb,
                  const float* __restrict__ wxw,
                  const float* __restrict__ wxb,
                  const float* __restrict__ whb,
                  float* __restrict__ tab)
{
    const int j  = threadIdx.x;          // output unit 0..255
    const int v0 = blockIdx.x * 32;
    const int rows = min(32, VOCAB - v0);

    __shared__ float ebuf[32 * D_EMB];   // 16 KB
    for (int i = j; i < rows * D_EMB; i += 256)
        ebuf[i] = emb[(size_t)v0 * D_EMB + i];
    __syncthreads();

    float acc[32];
#pragma unroll
    for (int r = 0; r < 32; ++r) acc[r] = 0.f;

#pragma unroll 8
    for (int d = 0; d < D_EMB; ++d) {
        float wxv = wxw[d * HID + j];    // coalesced
#pragma unroll
        for (int r = 0; r < 32; ++r)
            acc[r] = fmaf(ebuf[r * D_EMB + d], wxv, acc[r]); // LDS broadcast
    }

    const float bb = wxb[j] + whb[j];
    for (int r = 0; r < rows; ++r)
        tab[(size_t)(v0 + r) * HID + j] = acc[r] + bb;       // coalesced
}

__device__ __forceinline__ float fast_tanh(float x) {
    // tanh(x) = 1 - 2/(e^{2x}+1); v_exp_f32-based, <1e-6 abs err.
    float e2 = __expf(2.f * x);
    return 1.f - 2.f / (e2 + 1.f);
}

// ---------------------------------------------------------------------------
// Kernel 2 (main): one block per batch row, 512 threads.
// Thread (jg = tid>>3, kg = tid&7) owns 4 output columns (colb..colb+3) over
// the 32-wide k-range [kg*32, kg*32+32). Weights: 32 float4 in VGPRs
// (wv[u][e] = wh_w[k(u,e)][colb..colb+3]), loaded coalesced once.
// h read from LDS with rotation swizzle eff=(u+kg)&7: each ds_read_b128 has
// 8 distinct addresses in 8 distinct bank quads (conflict-free, 8-way bcast),
// and each 16B read feeds 16 FMAs (4x less LDS traffic than before).
// Partial sums reduced over kg via 3 shfl_xor rounds; lanes kg<4 finish
// column colb+kg (ax gather prefetched one step ahead), tanh, write h.
// One barrier per step, double-buffered h.
// ---------------------------------------------------------------------------
__global__ __launch_bounds__(512, 2)
void rnn_main_kernel(const int*   __restrict__ batch,
                     const float* __restrict__ whw,
                     const float* __restrict__ clfw,
                     const float* __restrict__ clfb,
                     const float* __restrict__ ax_tab,
                     float*       __restrict__ out)
{
    const int b    = blockIdx.x;
    const int tid  = threadIdx.x;
    const int kg   = tid & 7;            // k-group 0..7 (k range kg*32..+31)
    const int colb = (tid >> 3) * 4;     // first of 4 owned columns

    __shared__ float hbuf[2][HID];       // double-buffered hidden state
    __shared__ float sbuf[2][HID];       // epilogue scratch

    // --- one-time weight load into vector registers (coalesced float4) ---
    // wv[u][e] = wh_w[k][colb..colb+3] with k = kg*32 + ((u+kg)&7)*4 + e
    // (rotated order matches the swizzled h reads below).
    float4 wv[8][4];
#pragma unroll
    for (int u = 0; u < 8; ++u) {
        const int eff = (u + kg) & 7;
#pragma unroll
        for (int e = 0; e < 4; ++e) {
            const int k = kg * 32 + eff * 4 + e;
            wv[u][e] = *(const float4*)&whw[(size_t)k * HID + colb];
        }
    }

    if (tid < HID) hbuf[0][tid] = 0.f;

    const int* brow = batch + (size_t)b * T_LEN;
    const bool writer = (kg < 4);
    const int  wcol   = colb + (kg & 3);

    int tok_n = brow[0];
    float axv = 0.f;
    if (writer) axv = ax_tab[(size_t)tok_n * HID + wcol];   // ax for t=0
    tok_n = brow[1];
    __syncthreads();

    int cur = 0;
    for (int t = 0; t < T_LEN; ++t) {
        const int nxt = cur ^ 1;
        // --- prefetch for t+1 (hide L2/L3 gather latency under the matvec) ---
        const int tok_nn = (t + 2 < T_LEN) ? brow[t + 2] : 0;
        float ax_n = 0.f;
        if (writer && (t + 1 < T_LEN))
            ax_n = ax_tab[(size_t)tok_n * HID + wcol];

        // --- matvec partial: 8 swizzled LDS float4 reads, 128 FMAs ---
        float a0 = 0.f, a1 = 0.f, a2 = 0.f, a3 = 0.f;
        const float* hbase = &hbuf[cur][kg * 32];
#pragma unroll
        for (int u = 0; u < 8; ++u) {
            const int eff = (u + kg) & 7;
            const float4 h4 = *(const float4*)(hbase + eff * 4);
            a0 = fmaf(h4.x, wv[u][0].x, a0);
            a1 = fmaf(h4.x, wv[u][0].y, a1);
            a2 = fmaf(h4.x, wv[u][0].z, a2);
            a3 = fmaf(h4.x, wv[u][0].w, a3);
            a0 = fmaf(h4.y, wv[u][1].x, a0);
            a1 = fmaf(h4.y, wv[u][1].y, a1);
            a2 = fmaf(h4.y, wv[u][1].z, a2);
            a3 = fmaf(h4.y, wv[u][1].w, a3);
            a0 = fmaf(h4.z, wv[u][2].x, a0);
            a1 = fmaf(h4.z, wv[u][2].y, a1);
            a2 = fmaf(h4.z, wv[u][2].z, a2);
            a3 = fmaf(h4.z, wv[u][2].w, a3);
            a0 = fmaf(h4.w, wv[u][3].x, a0);
            a1 = fmaf(h4.w, wv[u][3].y, a1);
            a2 = fmaf(h4.w, wv[u][3].z, a2);
            a3 = fmaf(h4.w, wv[u][3].w, a3);
        }

        // --- reduce over the 8 kg lanes (lane bits 0..2) ---
#pragma unroll
        for (int m = 1; m <= 4; m <<= 1) {
            a0 += __shfl_xor(a0, m);
            a1 += __shfl_xor(a1, m);
            a2 += __shfl_xor(a2, m);
            a3 += __shfl_xor(a3, m);
        }

        if (writer) {
            const float s = (kg == 0) ? a0 : (kg == 1) ? a1 : (kg == 2) ? a2 : a3;
            const float h = fast_tanh(s + axv);   // biases folded into ax_tab
            hbuf[nxt][wcol] = h;
        }
        __syncthreads();   // h[nxt] visible; everyone done with h[cur]

        axv   = ax_n;
        tok_n = tok_nn;
        cur   = nxt;
    }

    // --- epilogue: out[b][c] = sum_j h[j] * clf_w[j][c] + clf_b[c] ---
    if (tid < HID) {
        const float h = hbuf[cur][tid];
        sbuf[0][tid] = h * clfw[tid * N_CLS + 0];
        sbuf[1][tid] = h * clfw[tid * N_CLS + 1];
    }
    __syncthreads();
    if (tid < 64) {
        float v = sbuf[0][tid] + sbuf[0][tid + 64] +
                  sbuf[0][tid + 128] + sbuf[0][tid + 192];
#pragma unroll
        for (int off = 32; off > 0; off >>= 1) v += __shfl_xor(v, off);
        if (tid == 0) out[b * N_CLS + 0] = v + clfb[0];
    } else if (tid < 128) {
        const int l = tid - 64;
        float v = sbuf[1][l] + sbuf[1][l + 64] +
                  sbuf[1][l + 128] + sbuf[1][l + 192];
#pragma unroll
        for (int off = 32; off > 0; off >>= 1) v += __shfl_xor(v, off);
        if (l == 0) out[b * N_CLS + 1] = v + clfb[1];
    }
}

// ---------------------------------------------------------------------------
// Fallback (workspace too small for the 51.5 MB table): previous working
// kernel, computes ax inline from the embedding row each step.
// ---------------------------------------------------------------------------
__global__ __launch_bounds__(512, 2)
void rnn_fallback_kernel(const int*   __restrict__ batch,
                         const float* __restrict__ emb,
                         const float* __restrict__ wxw,
                         const float* __restrict__ wxb,
                         const float* __restrict__ whw,
                         const float* __restrict__ whb,
                         const float* __restrict__ clfw,
                         const float* __restrict__ clfb,
                         float*       __restrict__ out)
{
    const int b    = blockIdx.x;
    const int tid  = threadIdx.x;
    const int j    = tid >> 1;
    const int half = tid & 1;
    const int k0   = half * 128;

    __shared__ float hbuf[2][HID];
    __shared__ float ebuf[2][D_EMB];

    float w[128];
#pragma unroll
    for (int k = 0; k < 128; ++k)
        w[k] = whw[(size_t)(k0 + k) * HID + j];

    float wx[64];
#pragma unroll
    for (int d = 0; d < 64; ++d)
        wx[d] = wxw[(size_t)(half * 64 + d) * HID + j];

    const float bj  = whb[j];
    const float axb = wxb[j];

    if (tid < HID) hbuf[0][tid] = 0.f;

    const int* brow = batch + (size_t)b * T_LEN;

    int tok_n = brow[0];
    if (tid < D_EMB) ebuf[0][tid] = emb[(size_t)tok_n * D_EMB + tid];
    tok_n = brow[1];
    __syncthreads();

    float h_j = 0.f;
    int cur = 0;
    for (int t = 0; t < T_LEN; ++t) {
        const int nxt = cur ^ 1;
        const int tok_nn = (t + 2 < T_LEN) ? brow[t + 2] : 0;
        float ev = 0.f;
        if (t + 1 < T_LEN && tid < D_EMB)
            ev = emb[(size_t)tok_n * D_EMB + tid];

        float a0 = 0.f, a1 = 0.f, a2 = 0.f, a3 = 0.f;
        const float4* hv = (const float4*)&hbuf[cur][k0];
#pragma unroll
        for (int i = 0; i < 32; ++i) {
            float4 h4 = hv[i];
            a0 = fmaf(h4.x, w[4 * i + 0], a0);
            a1 = fmaf(h4.y, w[4 * i + 1], a1);
            a2 = fmaf(h4.z, w[4 * i + 2], a2);
            a3 = fmaf(h4.w, w[4 * i + 3], a3);
        }
        const float4* evv = (const float4*)&ebuf[cur][half * 64];
#pragma unroll
        for (int i = 0; i < 16; ++i) {
            float4 e4 = evv[i];
            a0 = fmaf(e4.x, wx[4 * i + 0], a0);
            a1 = fmaf(e4.y, wx[4 * i + 1], a1);
            a2 = fmaf(e4.z, wx[4 * i + 2], a2);
            a3 = fmaf(e4.w, wx[4 * i + 3], a3);
        }
        float s = (a0 + a1) + (a2 + a3);
        s += __shfl_xor(s, 1);

        h_j = fast_tanh(s + bj + axb);

        if (half == 0) hbuf[nxt][j] = h_j;
        if (t + 1 < T_LEN && tid < D_EMB) ebuf[nxt][tid] = ev;
        __syncthreads();

        tok_n = tok_nn;
        cur   = nxt;
    }

    if (half == 0) {
        hbuf[0][j] = h_j * clfw[j * N_CLS + 0];
        hbuf[1][j] = h_j * clfw[j * N_CLS + 1];
    }
    __syncthreads();
    if (tid < 64) {
        float v = hbuf[0][tid] + hbuf[0][tid + 64] +
                  hbuf[0][tid + 128] + hbuf[0][tid + 192];
#pragma unroll
        for (int off = 32; off > 0; off >>= 1) v += __shfl_xor(v, off);
        if (tid == 0) out[b * N_CLS + 0] = v + clfb[0];
    } else if (tid < 128) {
        const int l = tid - 64;
        float v = hbuf[1][l] + hbuf[1][l + 64] +
                  hbuf[1][l + 128] + hbuf[1][l + 192];
#pragma unroll
        for (int off = 32; off > 0; off >>= 1) v += __shfl_xor(v, off);
        if (l == 0) out[b * N_CLS + 1] = v + clfb[1];
    }
}

// ---------------------------------------------------------------------------
extern "C" void kernel_launch(void* const* d_in, const int* in_sizes, int n_in,
                              void* d_out, int out_size, void* d_ws, size_t ws_size,
                              hipStream_t stream)
{
    const int*   batch = (const int*)  d_in[0];
    const float* emb   = (const float*)d_in[1];
    const float* wxw   = (const float*)d_in[2];
    const float* wxb   = (const float*)d_in[3];
    const float* whw   = (const float*)d_in[4];
    const float* whb   = (const float*)d_in[5];
    const float* clfw  = (const float*)d_in[6];
    const float* clfb  = (const float*)d_in[7];
    float* out = (float*)d_out;

    const size_t tab_bytes = (size_t)VOCAB * HID * sizeof(float);
    if (ws_size >= tab_bytes) {
        float* tab = (float*)d_ws;
        tabax_kernel<<<(VOCAB + 31) / 32, 256, 0, stream>>>(emb, wxw, wxb, whb, tab);
        rnn_main_kernel<<<BSZ, 512, 0, stream>>>(batch, whw, clfw, clfb, tab, out);
    } else {
        rnn_fallback_kernel<<<BSZ, 512, 0, stream>>>(batch, emb, wxw, wxb, whw, whb,
                                                     clfw, clfb, out);
    }
}

// Round 7
// 1634.321 us; speedup vs baseline: 1.3955x; 1.2611x over previous
//
#include <hip/hip_runtime.h>
#include <hip/hip_bf16.h>

// Problem constants (match reference).
#define VOCAB  50257
#define D_EMB  128
#define HID    256
#define N_CLS  2
#define BSZ    256
#define T_LEN  2048

// ---------------------------------------------------------------------------
// Kernel 1: tab[v][j] = sum_d emb_table[v][d] * wx_w[d][j] + wx_b[j] + wh_b[j]
// ---------------------------------------------------------------------------
__global__ __launch_bounds__(256)
void tabax_kernel(const float* __restrict__ emb,
                  const float* __restrict__ wxw,
                  const float* __restrict__ wxb,
                  const float* __restrict__ whb,
                  float* __restrict__ tab)
{
    const int j  = threadIdx.x;          // output unit 0..255
    const int v0 = blockIdx.x * 32;
    const int rows = min(32, VOCAB - v0);

    __shared__ float ebuf[32 * D_EMB];   // 16 KB
    for (int i = j; i < rows * D_EMB; i += 256)
        ebuf[i] = emb[(size_t)v0 * D_EMB + i];
    __syncthreads();

    float acc[32];
#pragma unroll
    for (int r = 0; r < 32; ++r) acc[r] = 0.f;

#pragma unroll 8
    for (int d = 0; d < D_EMB; ++d) {
        float wxv = wxw[d * HID + j];    // coalesced
#pragma unroll
        for (int r = 0; r < 32; ++r)
            acc[r] = fmaf(ebuf[r * D_EMB + d], wxv, acc[r]); // LDS broadcast
    }

    const float bb = wxb[j] + whb[j];
    for (int r = 0; r < rows; ++r)
        tab[(size_t)(v0 + r) * HID + j] = acc[r] + bb;       // coalesced
}

__device__ __forceinline__ float fast_tanh(float x) {
    float e2 = __expf(2.f * x);
    return 1.f - 2.f / (e2 + 1.f);
}

// ---------------------------------------------------------------------------
// Kernel 2 (main): one block per batch row, 512 threads.
// Thread (cg = tid>>4, kg = tid&15) owns cols [cg*8, cg*8+8) over k in
// [kg*16, kg*16+16). Weights W[4][4][8] = 128 f32 pinned into VGPRs via an
// asm value-barrier (defeats load-rematerialization: VGPR_Count must be
// ~180+, WRITE_SIZE must stay tiny). Each swizzled ds_read_b128 of h feeds
// 32 FMAs. k-reduce over 16 lanes = halving tree (8 shfl_xor + 8 add);
// both lanes {2c,2c+1} end with col c0+c; even lane writes h.
// Bank swizzle eff=(e+(kg>>2))&3: 2 addrs per bank-quad = conflict-free.
// ---------------------------------------------------------------------------
__global__ __launch_bounds__(512, 2)
void rnn_main_kernel(const int*   __restrict__ batch,
                     const float* __restrict__ whw,
                     const float* __restrict__ clfw,
                     const float* __restrict__ clfb,
                     const float* __restrict__ ax_tab,
                     float*       __restrict__ out)
{
    const int b   = blockIdx.x;
    const int tid = threadIdx.x;
    const int kg  = tid & 15;            // k-group: k in [kg*16, kg*16+16)
    const int cg  = tid >> 4;            // col-group: cols [cg*8, cg*8+8)
    const int c0  = cg * 8;
    const int kb  = kg * 16;
    const int rot = (kg >> 2) & 3;       // bank-swizzle rotation

    __shared__ float hbuf[2][HID];       // double-buffered hidden state
    __shared__ float sbuf[2][HID];       // epilogue scratch

    // --- one-time weight load: W[e][m][i] = wh_w[kb+((e+rot)&3)*4+m][c0+i] ---
    float W[4][4][8];
#pragma unroll
    for (int e = 0; e < 4; ++e) {
        const int swz = (e + rot) & 3;
#pragma unroll
        for (int m = 0; m < 4; ++m) {
            const int k = kb + swz * 4 + m;
            const float4 lo = *(const float4*)&whw[(size_t)k * HID + c0];
            const float4 hi = *(const float4*)&whw[(size_t)k * HID + c0 + 4];
            W[e][m][0] = lo.x; W[e][m][1] = lo.y; W[e][m][2] = lo.z; W[e][m][3] = lo.w;
            W[e][m][4] = hi.x; W[e][m][5] = hi.y; W[e][m][6] = hi.z; W[e][m][7] = hi.w;
        }
    }
    // Pin: asm redefines each value -> compiler cannot rematerialize the
    // global loads inside the loop; weights MUST stay resident in VGPRs.
#pragma unroll
    for (int e = 0; e < 4; ++e)
#pragma unroll
        for (int m = 0; m < 4; ++m)
#pragma unroll
            for (int i = 0; i < 8; i += 4)
                asm volatile("" : "+v"(W[e][m][i + 0]), "+v"(W[e][m][i + 1]),
                                  "+v"(W[e][m][i + 2]), "+v"(W[e][m][i + 3]));

    // LDS byte offsets of the 4 swizzled float4 reads (within one h buffer).
    int lds_off[4];
#pragma unroll
    for (int e = 0; e < 4; ++e) lds_off[e] = kg * 64 + ((e + rot) & 3) * 16;

    const int  mycol = c0 + ((kg >> 1) & 7);   // column this lane finalizes
    const bool wr    = (kg & 1) == 0;          // even lane of the pair writes

    if (tid < HID) hbuf[0][tid] = 0.f;

    const int* brow = batch + (size_t)b * T_LEN;
    int tok_n = brow[0];
    float axv = ax_tab[(size_t)tok_n * HID + mycol];   // ax for t=0
    tok_n = brow[1];
    __syncthreads();

    int cur = 0;
    for (int t = 0; t < T_LEN; ++t) {
        const int nxt = cur ^ 1;
        // prefetch token t+2 and ax row t+1 (tok index 0 is always valid)
        const int tok_nn = (t + 2 < T_LEN) ? brow[t + 2] : 0;
        const float ax_n = ax_tab[(size_t)tok_n * HID + mycol];

        // --- matvec partials: 4 swizzled ds_read_b128, 128 FMAs ---
        float acc[8];
#pragma unroll
        for (int i = 0; i < 8; ++i) acc[i] = 0.f;

        const char* hb = (const char*)&hbuf[cur][0];
#pragma unroll
        for (int e = 0; e < 4; ++e) {
            const float4 h4 = *(const float4*)(hb + lds_off[e]);
            const float hm[4] = {h4.x, h4.y, h4.z, h4.w};
#pragma unroll
            for (int m = 0; m < 4; ++m)
#pragma unroll
                for (int i = 0; i < 8; ++i)
                    acc[i] = fmaf(hm[m], W[e][m][i], acc[i]);
        }

        // --- halving-tree reduce over the 16 kg lanes ---
#pragma unroll
        for (int i = 0; i < 4; ++i) {              // mask 8: 8 vals -> 4
            const float send = (kg & 8) ? acc[i] : acc[i + 4];
            const float keep = (kg & 8) ? acc[i + 4] : acc[i];
            acc[i] = keep + __shfl_xor(send, 8);
        }
#pragma unroll
        for (int i = 0; i < 2; ++i) {              // mask 4: 4 -> 2
            const float send = (kg & 4) ? acc[i] : acc[i + 2];
            const float keep = (kg & 4) ? acc[i + 2] : acc[i];
            acc[i] = keep + __shfl_xor(send, 4);
        }
        {                                          // mask 2: 2 -> 1
            const float send = (kg & 2) ? acc[0] : acc[1];
            const float keep = (kg & 2) ? acc[1] : acc[0];
            acc[0] = keep + __shfl_xor(send, 2);
        }
        acc[0] += __shfl_xor(acc[0], 1);           // mask 1: duplicate sum

        const float h = fast_tanh(acc[0] + axv);   // biases folded into ax_tab
        if (wr) hbuf[nxt][mycol] = h;
        __syncthreads();

        axv   = ax_n;
        tok_n = tok_nn;
        cur   = nxt;
    }

    // --- epilogue: out[b][c] = sum_j h[j] * clf_w[j][c] + clf_b[c] ---
    if (tid < HID) {
        const float h = hbuf[cur][tid];
        sbuf[0][tid] = h * clfw[tid * N_CLS + 0];
        sbuf[1][tid] = h * clfw[tid * N_CLS + 1];
    }
    __syncthreads();
    if (tid < 64) {
        float v = sbuf[0][tid] + sbuf[0][tid + 64] +
                  sbuf[0][tid + 128] + sbuf[0][tid + 192];
#pragma unroll
        for (int off = 32; off > 0; off >>= 1) v += __shfl_xor(v, off);
        if (tid == 0) out[b * N_CLS + 0] = v + clfb[0];
    } else if (tid < 128) {
        const int l = tid - 64;
        float v = sbuf[1][l] + sbuf[1][l + 64] +
                  sbuf[1][l + 128] + sbuf[1][l + 192];
#pragma unroll
        for (int off = 32; off > 0; off >>= 1) v += __shfl_xor(v, off);
        if (l == 0) out[b * N_CLS + 1] = v + clfb[1];
    }
}

// ---------------------------------------------------------------------------
// Fallback (workspace too small for the 51.5 MB table).
// ---------------------------------------------------------------------------
__global__ __launch_bounds__(512, 2)
void rnn_fallback_kernel(const int*   __restrict__ batch,
                         const float* __restrict__ emb,
                         const float* __restrict__ wxw,
                         const float* __restrict__ wxb,
                         const float* __restrict__ whw,
                         const float* __restrict__ whb,
                         const float* __restrict__ clfw,
                         const float* __restrict__ clfb,
                         float*       __restrict__ out)
{
    const int b    = blockIdx.x;
    const int tid  = threadIdx.x;
    const int j    = tid >> 1;
    const int half = tid & 1;
    const int k0   = half * 128;

    __shared__ float hbuf[2][HID];
    __shared__ float ebuf[2][D_EMB];

    float w[128];
#pragma unroll
    for (int k = 0; k < 128; ++k)
        w[k] = whw[(size_t)(k0 + k) * HID + j];

    float wx[64];
#pragma unroll
    for (int d = 0; d < 64; ++d)
        wx[d] = wxw[(size_t)(half * 64 + d) * HID + j];

    const float bj  = whb[j];
    const float axb = wxb[j];

    if (tid < HID) hbuf[0][tid] = 0.f;

    const int* brow = batch + (size_t)b * T_LEN;

    int tok_n = brow[0];
    if (tid < D_EMB) ebuf[0][tid] = emb[(size_t)tok_n * D_EMB + tid];
    tok_n = brow[1];
    __syncthreads();

    float h_j = 0.f;
    int cur = 0;
    for (int t = 0; t < T_LEN; ++t) {
        const int nxt = cur ^ 1;
        const int tok_nn = (t + 2 < T_LEN) ? brow[t + 2] : 0;
        float ev = 0.f;
        if (t + 1 < T_LEN && tid < D_EMB)
            ev = emb[(size_t)tok_n * D_EMB + tid];

        float a0 = 0.f, a1 = 0.f, a2 = 0.f, a3 = 0.f;
        const float4* hv = (const float4*)&hbuf[cur][k0];
#pragma unroll
        for (int i = 0; i < 32; ++i) {
            float4 h4 = hv[i];
            a0 = fmaf(h4.x, w[4 * i + 0], a0);
            a1 = fmaf(h4.y, w[4 * i + 1], a1);
            a2 = fmaf(h4.z, w[4 * i + 2], a2);
            a3 = fmaf(h4.w, w[4 * i + 3], a3);
        }
        const float4* evv = (const float4*)&ebuf[cur][half * 64];
#pragma unroll
        for (int i = 0; i < 16; ++i) {
            float4 e4 = evv[i];
            a0 = fmaf(e4.x, wx[4 * i + 0], a0);
            a1 = fmaf(e4.y, wx[4 * i + 1], a1);
            a2 = fmaf(e4.z, wx[4 * i + 2], a2);
            a3 = fmaf(e4.w, wx[4 * i + 3], a3);
        }
        float s = (a0 + a1) + (a2 + a3);
        s += __shfl_xor(s, 1);

        h_j = fast_tanh(s + bj + axb);

        if (half == 0) hbuf[nxt][j] = h_j;
        if (t + 1 < T_LEN && tid < D_EMB) ebuf[nxt][tid] = ev;
        __syncthreads();

        tok_n = tok_nn;
        cur   = nxt;
    }

    if (half == 0) {
        hbuf[0][j] = h_j * clfw[j * N_CLS + 0];
        hbuf[1][j] = h_j * clfw[j * N_CLS + 1];
    }
    __syncthreads();
    if (tid < 64) {
        float v = hbuf[0][tid] + hbuf[0][tid + 64] +
                  hbuf[0][tid + 128] + hbuf[0][tid + 192];
#pragma unroll
        for (int off = 32; off > 0; off >>= 1) v += __shfl_xor(v, off);
        if (tid == 0) out[b * N_CLS + 0] = v + clfb[0];
    } else if (tid < 128) {
        const int l = tid - 64;
        float v = hbuf[1][l] + hbuf[1][l + 64] +
                  hbuf[1][l + 128] + hbuf[1][l + 192];
#pragma unroll
        for (int off = 32; off > 0; off >>= 1) v += __shfl_xor(v, off);
        if (l == 0) out[b * N_CLS + 1] = v + clfb[1];
    }
}

// ---------------------------------------------------------------------------
extern "C" void kernel_launch(void* const* d_in, const int* in_sizes, int n_in,
                              void* d_out, int out_size, void* d_ws, size_t ws_size,
                              hipStream_t stream)
{
    const int*   batch = (const int*)  d_in[0];
    const float* emb   = (const float*)d_in[1];
    const float* wxw   = (const float*)d_in[2];
    const float* wxb   = (const float*)d_in[3];
    const float* whw   = (const float*)d_in[4];
    const float* whb   = (const float*)d_in[5];
    const float* clfw  = (const float*)d_in[6];
    const float* clfb  = (const float*)d_in[7];
    float* out = (float*)d_out;

    const size_t tab_bytes = (size_t)VOCAB * HID * sizeof(float);
    if (ws_size >= tab_bytes) {
        float* tab = (float*)d_ws;
        tabax_kernel<<<(VOCAB + 31) / 32, 256, 0, stream>>>(emb, wxw, wxb, whb, tab);
        rnn_main_kernel<<<BSZ, 512, 0, stream>>>(batch, whw, clfw, clfb, tab, out);
    } else {
        rnn_fallback_kernel<<<BSZ, 512, 0, stream>>>(batch, emb, wxw, wxb, whw, whb,
                                                     clfw, clfb, out);
    }
}

// Round 9
// 1631.166 us; speedup vs baseline: 1.3982x; 1.0019x over previous
//
#include <hip/hip_runtime.h>
#include <hip/hip_bf16.h>

// Problem constants (match reference).
#define VOCAB  50257
#define D_EMB  128
#define HID    256
#define N_CLS  2
#define BSZ    256
#define T_LEN  2048

// ---------------------------------------------------------------------------
// Kernel 1: tab[v][j] = sum_d emb_table[v][d] * wx_w[d][j] + wx_b[j] + wh_b[j]
// ---------------------------------------------------------------------------
__global__ __launch_bounds__(256)
void tabax_kernel(const float* __restrict__ emb,
                  const float* __restrict__ wxw,
                  const float* __restrict__ wxb,
                  const float* __restrict__ whb,
                  float* __restrict__ tab)
{
    const int j  = threadIdx.x;          // output unit 0..255
    const int v0 = blockIdx.x * 32;
    const int rows = min(32, VOCAB - v0);

    __shared__ float ebuf[32 * D_EMB];   // 16 KB
    for (int i = j; i < rows * D_EMB; i += 256)
        ebuf[i] = emb[(size_t)v0 * D_EMB + i];
    __syncthreads();

    float acc[32];
#pragma unroll
    for (int r = 0; r < 32; ++r) acc[r] = 0.f;

#pragma unroll 8
    for (int d = 0; d < D_EMB; ++d) {
        float wxv = wxw[d * HID + j];    // coalesced
#pragma unroll
        for (int r = 0; r < 32; ++r)
            acc[r] = fmaf(ebuf[r * D_EMB + d], wxv, acc[r]); // LDS broadcast
    }

    const float bb = wxb[j] + whb[j];
    for (int r = 0; r < rows; ++r)
        tab[(size_t)(v0 + r) * HID + j] = acc[r] + bb;       // coalesced
}

__device__ __forceinline__ float fast_tanh(float x) {
    float e2 = __expf(2.f * x);
    return 1.f - 2.f / (e2 + 1.f);
}

// ---------------------------------------------------------------------------
// Kernel 2 (main): one block per batch row, 512 threads.
// Thread (cg = tid>>4, kg = tid&15) owns cols [cg*8, cg*8+8) over k in
// [kg*16, kg*16+16). Weights W[4][4][8] = 128 f32 pinned into registers via
// asm value-barrier. __launch_bounds__(512, 1): grid is fixed at 1 block/CU
// (256 blocks x 8 waves), so declaring 1 wave/EU min costs no occupancy but
// raises the arch-VGPR budget to 512 -- removing the RA's reason to stash W
// in AGPRs (R7: VGPR_Count=84 + ~128 v_accvgpr_read/step, gfx950 VOP2 cannot
// source AGPRs directly so each use paid a copy). Expect VGPR_Count >= 200.
// Each swizzled ds_read_b128 of h feeds 32 FMAs. k-reduce over 16 lanes =
// halving tree. One barrier per step, double-buffered h.
// Bank swizzle eff=(e+(kg>>2))&3: 2 addrs per bank-quad = conflict-free.
// ---------------------------------------------------------------------------
__global__ __launch_bounds__(512, 1)
void rnn_main_kernel(const int*   __restrict__ batch,
                     const float* __restrict__ whw,
                     const float* __restrict__ clfw,
                     const float* __restrict__ clfb,
                     const float* __restrict__ ax_tab,
                     float*       __restrict__ out)
{
    const int b   = blockIdx.x;
    const int tid = threadIdx.x;
    const int kg  = tid & 15;            // k-group: k in [kg*16, kg*16+16)
    const int cg  = tid >> 4;            // col-group: cols [cg*8, cg*8+8)
    const int c0  = cg * 8;
    const int kb  = kg * 16;
    const int rot = (kg >> 2) & 3;       // bank-swizzle rotation

    __shared__ float hbuf[2][HID];       // double-buffered hidden state
    __shared__ float sbuf[2][HID];       // epilogue scratch

    // --- one-time weight load: W[e][m][i] = wh_w[kb+((e+rot)&3)*4+m][c0+i] ---
    float W[4][4][8];
#pragma unroll
    for (int e = 0; e < 4; ++e) {
        const int swz = (e + rot) & 3;
#pragma unroll
        for (int m = 0; m < 4; ++m) {
            const int k = kb + swz * 4 + m;
            const float4 lo = *(const float4*)&whw[(size_t)k * HID + c0];
            const float4 hi = *(const float4*)&whw[(size_t)k * HID + c0 + 4];
            W[e][m][0] = lo.x; W[e][m][1] = lo.y; W[e][m][2] = lo.z; W[e][m][3] = lo.w;
            W[e][m][4] = hi.x; W[e][m][5] = hi.y; W[e][m][6] = hi.z; W[e][m][7] = hi.w;
        }
    }
    // Pin: asm redefines each value -> compiler cannot rematerialize the
    // global loads inside the loop; weights must stay register-resident.
#pragma unroll
    for (int e = 0; e < 4; ++e)
#pragma unroll
        for (int m = 0; m < 4; ++m)
#pragma unroll
            for (int i = 0; i < 8; i += 4)
                asm volatile("" : "+v"(W[e][m][i + 0]), "+v"(W[e][m][i + 1]),
                                  "+v"(W[e][m][i + 2]), "+v"(W[e][m][i + 3]));

    // LDS byte offsets of the 4 swizzled float4 reads (within one h buffer).
    int lds_off[4];
#pragma unroll
    for (int e = 0; e < 4; ++e) lds_off[e] = kg * 64 + ((e + rot) & 3) * 16;

    const int  mycol = c0 + ((kg >> 1) & 7);   // column this lane finalizes
    const bool wr    = (kg & 1) == 0;          // even lane of the pair writes

    if (tid < HID) hbuf[0][tid] = 0.f;

    const int* brow = batch + (size_t)b * T_LEN;
    int tok_n = brow[0];
    float axv = ax_tab[(size_t)tok_n * HID + mycol];   // ax for t=0
    tok_n = brow[1];
    __syncthreads();

    int cur = 0;
    for (int t = 0; t < T_LEN; ++t) {
        const int nxt = cur ^ 1;
        // prefetch token t+2 and ax row t+1 (tok index 0 is always valid)
        const int tok_nn = (t + 2 < T_LEN) ? brow[t + 2] : 0;
        const float ax_n = ax_tab[(size_t)tok_n * HID + mycol];

        // --- matvec partials: 4 swizzled ds_read_b128, 128 FMAs ---
        float acc[8];
#pragma unroll
        for (int i = 0; i < 8; ++i) acc[i] = 0.f;

        const char* hb = (const char*)&hbuf[cur][0];
#pragma unroll
        for (int e = 0; e < 4; ++e) {
            const float4 h4 = *(const float4*)(hb + lds_off[e]);
            const float hm[4] = {h4.x, h4.y, h4.z, h4.w};
#pragma unroll
            for (int m = 0; m < 4; ++m)
#pragma unroll
                for (int i = 0; i < 8; ++i)
                    acc[i] = fmaf(hm[m], W[e][m][i], acc[i]);
        }

        // --- halving-tree reduce over the 16 kg lanes ---
#pragma unroll
        for (int i = 0; i < 4; ++i) {              // mask 8: 8 vals -> 4
            const float send = (kg & 8) ? acc[i] : acc[i + 4];
            const float keep = (kg & 8) ? acc[i + 4] : acc[i];
            acc[i] = keep + __shfl_xor(send, 8);
        }
#pragma unroll
        for (int i = 0; i < 2; ++i) {              // mask 4: 4 -> 2
            const float send = (kg & 4) ? acc[i] : acc[i + 2];
            const float keep = (kg & 4) ? acc[i + 2] : acc[i];
            acc[i] = keep + __shfl_xor(send, 4);
        }
        {                                          // mask 2: 2 -> 1
            const float send = (kg & 2) ? acc[0] : acc[1];
            const float keep = (kg & 2) ? acc[1] : acc[0];
            acc[0] = keep + __shfl_xor(send, 2);
        }
        acc[0] += __shfl_xor(acc[0], 1);           // mask 1: duplicate sum

        const float h = fast_tanh(acc[0] + axv);   // biases folded into ax_tab
        if (wr) hbuf[nxt][mycol] = h;
        __syncthreads();

        axv   = ax_n;
        tok_n = tok_nn;
        cur   = nxt;
    }

    // --- epilogue: out[b][c] = sum_j h[j] * clf_w[j][c] + clf_b[c] ---
    if (tid < HID) {
        const float h = hbuf[cur][tid];
        sbuf[0][tid] = h * clfw[tid * N_CLS + 0];
        sbuf[1][tid] = h * clfw[tid * N_CLS + 1];
    }
    __syncthreads();
    if (tid < 64) {
        float v = sbuf[0][tid] + sbuf[0][tid + 64] +
                  sbuf[0][tid + 128] + sbuf[0][tid + 192];
#pragma unroll
        for (int off = 32; off > 0; off >>= 1) v += __shfl_xor(v, off);
        if (tid == 0) out[b * N_CLS + 0] = v + clfb[0];
    } else if (tid < 128) {
        const int l = tid - 64;
        float v = sbuf[1][l] + sbuf[1][l + 64] +
                  sbuf[1][l + 128] + sbuf[1][l + 192];
#pragma unroll
        for (int off = 32; off > 0; off >>= 1) v += __shfl_xor(v, off);
        if (l == 0) out[b * N_CLS + 1] = v + clfb[1];
    }
}

// ---------------------------------------------------------------------------
// Fallback (workspace too small for the 51.5 MB table).
// ---------------------------------------------------------------------------
__global__ __launch_bounds__(512, 2)
void rnn_fallback_kernel(const int*   __restrict__ batch,
                         const float* __restrict__ emb,
                         const float* __restrict__ wxw,
                         const float* __restrict__ wxb,
                         const float* __restrict__ whw,
                         const float* __restrict__ whb,
                         const float* __restrict__ clfw,
                         const float* __restrict__ clfb,
                         float*       __restrict__ out)
{
    const int b    = blockIdx.x;
    const int tid  = threadIdx.x;
    const int j    = tid >> 1;
    const int half = tid & 1;
    const int k0   = half * 128;

    __shared__ float hbuf[2][HID];
    __shared__ float ebuf[2][D_EMB];

    float w[128];
#pragma unroll
    for (int k = 0; k < 128; ++k)
        w[k] = whw[(size_t)(k0 + k) * HID + j];

    float wx[64];
#pragma unroll
    for (int d = 0; d < 64; ++d)
        wx[d] = wxw[(size_t)(half * 64 + d) * HID + j];

    const float bj  = whb[j];
    const float axb = wxb[j];

    if (tid < HID) hbuf[0][tid] = 0.f;

    const int* brow = batch + (size_t)b * T_LEN;

    int tok_n = brow[0];
    if (tid < D_EMB) ebuf[0][tid] = emb[(size_t)tok_n * D_EMB + tid];
    tok_n = brow[1];
    __syncthreads();

    float h_j = 0.f;
    int cur = 0;
    for (int t = 0; t < T_LEN; ++t) {
        const int nxt = cur ^ 1;
        const int tok_nn = (t + 2 < T_LEN) ? brow[t + 2] : 0;
        float ev = 0.f;
        if (t + 1 < T_LEN && tid < D_EMB)
            ev = emb[(size_t)tok_n * D_EMB + tid];

        float a0 = 0.f, a1 = 0.f, a2 = 0.f, a3 = 0.f;
        const float4* hv = (const float4*)&hbuf[cur][k0];
#pragma unroll
        for (int i = 0; i < 32; ++i) {
            float4 h4 = hv[i];
            a0 = fmaf(h4.x, w[4 * i + 0], a0);
            a1 = fmaf(h4.y, w[4 * i + 1], a1);
            a2 = fmaf(h4.z, w[4 * i + 2], a2);
            a3 = fmaf(h4.w, w[4 * i + 3], a3);
        }
        const float4* evv = (const float4*)&ebuf[cur][half * 64];
#pragma unroll
        for (int i = 0; i < 16; ++i) {
            float4 e4 = evv[i];
            a0 = fmaf(e4.x, wx[4 * i + 0], a0);
            a1 = fmaf(e4.y, wx[4 * i + 1], a1);
            a2 = fmaf(e4.z, wx[4 * i + 2], a2);
            a3 = fmaf(e4.w, wx[4 * i + 3], a3);
        }
        float s = (a0 + a1) + (a2 + a3);
        s += __shfl_xor(s, 1);

        h_j = fast_tanh(s + bj + axb);

        if (half == 0) hbuf[nxt][j] = h_j;
        if (t + 1 < T_LEN && tid < D_EMB) ebuf[nxt][tid] = ev;
        __syncthreads();

        tok_n = tok_nn;
        cur   = nxt;
    }

    if (half == 0) {
        hbuf[0][j] = h_j * clfw[j * N_CLS + 0];
        hbuf[1][j] = h_j * clfw[j * N_CLS + 1];
    }
    __syncthreads();
    if (tid < 64) {
        float v = hbuf[0][tid] + hbuf[0][tid + 64] +
                  hbuf[0][tid + 128] + hbuf[0][tid + 192];
#pragma unroll
        for (int off = 32; off > 0; off >>= 1) v += __shfl_xor(v, off);
        if (tid == 0) out[b * N_CLS + 0] = v + clfb[0];
    } else if (tid < 128) {
        const int l = tid - 64;
        float v = hbuf[1][l] + hbuf[1][l + 64] +
                  hbuf[1][l + 128] + hbuf[1][l + 192];
#pragma unroll
        for (int off = 32; off > 0; off >>= 1) v += __shfl_xor(v, off);
        if (l == 0) out[b * N_CLS + 1] = v + clfb[1];
    }
}

// ---------------------------------------------------------------------------
extern "C" void kernel_launch(void* const* d_in, const int* in_sizes, int n_in,
                              void* d_out, int out_size, void* d_ws, size_t ws_size,
                              hipStream_t stream)
{
    const int*   batch = (const int*)  d_in[0];
    const float* emb   = (const float*)d_in[1];
    const float* wxw   = (const float*)d_in[2];
    const float* wxb   = (const float*)d_in[3];
    const float* whw   = (const float*)d_in[4];
    const float* whb   = (const float*)d_in[5];
    const float* clfw  = (const float*)d_in[6];
    const float* clfb  = (const float*)d_in[7];
    float* out = (float*)d_out;

    const size_t tab_bytes = (size_t)VOCAB * HID * sizeof(float);
    if (ws_size >= tab_bytes) {
        float* tab = (float*)d_ws;
        tabax_kernel<<<(VOCAB + 31) / 32, 256, 0, stream>>>(emb, wxw, wxb, whb, tab);
        rnn_main_kernel<<<BSZ, 512, 0, stream>>>(batch, whw, clfw, clfb, tab, out);
    } else {
        rnn_fallback_kernel<<<BSZ, 512, 0, stream>>>(batch, emb, wxw, wxb, whw, whb,
                                                     clfw, clfb, out);
    }
}